// Round 1
// baseline (1613.065 us; speedup 1.0000x reference)
//
#include <hip/hip_runtime.h>

#define NN 8192       // nodes
#define KM 4          // mixture components
#define NE 262144     // edges
#define DD 128        // feature dim (in == out)

// ---------------------------------------------------------------------------
// ws layout (floats):
//   ew   [NE]        edge mixture weights
//   deg  [NN]        degree accumulator (edges only; +1 self-loop added later)
//   dinv [NN]        rsqrt degree
//   xw   [NN*DD]     x @ W^T
// ---------------------------------------------------------------------------

// Kernel 1: per-edge mixture weight + degree accumulation.
__global__ __launch_bounds__(256) void edge_w_kernel(
        const float* __restrict__ A,       // [KM, NN, NN]
        const int*   __restrict__ ei,      // [2, NE]
        const float* __restrict__ wlog,    // [KM]
        float* __restrict__ ew,
        float* __restrict__ deg) {
    int e = blockIdx.x * blockDim.x + threadIdx.x;
    if (e >= NE) return;

    // softmax over 4 logits (uniform across threads -> scalarized by compiler)
    float l0 = wlog[0], l1 = wlog[1], l2 = wlog[2], l3 = wlog[3];
    float m = fmaxf(fmaxf(l0, l1), fmaxf(l2, l3));
    float e0 = __expf(l0 - m), e1 = __expf(l1 - m),
          e2 = __expf(l2 - m), e3 = __expf(l3 - m);
    float inv = 1.0f / (e0 + e1 + e2 + e3);

    int r = ei[e];
    int c = ei[NE + e];
    size_t off = (size_t)r * NN + (size_t)c;
    const size_t slab = (size_t)NN * NN;
    float v = e0 * A[off] + e1 * A[off + slab] + e2 * A[off + 2 * slab]
            + e3 * A[off + 3 * slab];
    v *= inv;
    ew[e] = v;
    unsafeAtomicAdd(&deg[c], v);   // HW global_atomic_add_f32
}

// Kernel 2: xw = x @ W^T  (fp32, vector ALU — no fp32 MFMA on CDNA4).
// Block: 32 rows x 128 cols, 256 threads, acc[4][4]/thread.
// W staged transposed in LDS in two K-chunks of 64 (pad 132 -> conflict-free
// ds_read_b128 in the inner loop; the 8-way conflict on the one-time
// transposed store is negligible: 32 store instrs/chunk).
#define GEMM_ROWS 32
__global__ __launch_bounds__(256) void xw_gemm_kernel(
        const float* __restrict__ x,    // [NN, DD]
        const float* __restrict__ Wm,   // [DD, DD] row-major (D_OUT, D_IN)
        float* __restrict__ xw) {       // [NN, DD]
    __shared__ float Wt[64 * 132];          // Wt[kk*132 + o] = W[o][kb+kk]
    __shared__ float Xs[GEMM_ROWS * DD];    // row-major x tile

    const int t = threadIdx.x;
    const int row0 = blockIdx.x * GEMM_ROWS;

    // stage x rows, coalesced float4
    {
        const float4* src = (const float4*)(x + (size_t)row0 * DD);
        float4* dst = (float4*)Xs;
        for (int i = t; i < GEMM_ROWS * (DD / 4); i += 256) dst[i] = src[i];
    }

    const int tx = t & 31;
    const int ty = t >> 5;
    const int o0 = tx * 4;
    float acc[4][4] = {};

    for (int kb = 0; kb < DD; kb += 64) {
        __syncthreads();
        // load W chunk transposed: lanes read contiguous W[o][kb..kb+63]
        for (int idx = t; idx < DD * 64; idx += 256) {
            int o = idx >> 6;
            int i = idx & 63;
            Wt[i * 132 + o] = Wm[o * DD + kb + i];
        }
        __syncthreads();
        #pragma unroll 8
        for (int kk = 0; kk < 64; ++kk) {
            float4 wv = *(const float4*)&Wt[kk * 132 + o0];  // b128, conflict-free
            int kg = kb + kk;
            #pragma unroll
            for (int rr = 0; rr < 4; ++rr) {
                float xv = Xs[(ty * 4 + rr) * DD + kg];      // 2-addr broadcast: free
                acc[rr][0] = fmaf(xv, wv.x, acc[rr][0]);
                acc[rr][1] = fmaf(xv, wv.y, acc[rr][1]);
                acc[rr][2] = fmaf(xv, wv.z, acc[rr][2]);
                acc[rr][3] = fmaf(xv, wv.w, acc[rr][3]);
            }
        }
    }

    #pragma unroll
    for (int rr = 0; rr < 4; ++rr) {
        size_t r = (size_t)row0 + ty * 4 + rr;
        *(float4*)&xw[r * DD + o0] =
            make_float4(acc[rr][0], acc[rr][1], acc[rr][2], acc[rr][3]);
    }
}

// Kernel 3: dinv = rsqrt(deg + 1)  (self-loop weight 1.0; deg >= 1 always),
// out = b + dinv^2 * xw  (self-loop message fused; also initializes out).
__global__ __launch_bounds__(256) void node_init_kernel(
        const float* __restrict__ deg,
        const float* __restrict__ xw,
        const float* __restrict__ b,
        float* __restrict__ dinv,
        float* __restrict__ out) {
    int idx = blockIdx.x * blockDim.x + threadIdx.x;  // over NN*32 float4s
    int i  = idx >> 5;          // node
    int d4 = idx & 31;          // float4 within row
    float dv = rsqrtf(deg[i] + 1.0f);
    if (d4 == 0) dinv[i] = dv;
    float s = dv * dv;
    float4 xv = *(const float4*)&xw[(size_t)i * DD + d4 * 4];
    float4 bv = *(const float4*)&b[d4 * 4];
    float4 ov;
    ov.x = bv.x + s * xv.x;
    ov.y = bv.y + s * xv.y;
    ov.z = bv.z + s * xv.z;
    ov.w = bv.w + s * xv.w;
    *(float4*)&out[(size_t)i * DD + d4 * 4] = ov;
}

// Kernel 4: edge aggregation. 32 lanes per edge, float4 per lane,
// out[c] += dinv[r]*ew*dinv[c] * xw[r] via HW f32 atomics.
__global__ __launch_bounds__(256) void aggregate_kernel(
        const int*   __restrict__ ei,
        const float* __restrict__ ew,
        const float* __restrict__ dinv,
        const float* __restrict__ xw,
        float* __restrict__ out) {
    int idx  = blockIdx.x * blockDim.x + threadIdx.x;
    int e    = idx >> 5;
    int lane = idx & 31;
    if (e >= NE) return;

    int r = ei[e];
    int c = ei[NE + e];
    float norm = dinv[r] * ew[e] * dinv[c];

    float4 v = *(const float4*)&xw[(size_t)r * DD + lane * 4];
    float* op = &out[(size_t)c * DD + lane * 4];
    unsafeAtomicAdd(op + 0, norm * v.x);
    unsafeAtomicAdd(op + 1, norm * v.y);
    unsafeAtomicAdd(op + 2, norm * v.z);
    unsafeAtomicAdd(op + 3, norm * v.w);
}

extern "C" void kernel_launch(void* const* d_in, const int* in_sizes, int n_in,
                              void* d_out, int out_size, void* d_ws, size_t ws_size,
                              hipStream_t stream) {
    const float* x    = (const float*)d_in[0];   // [NN, DD]
    const float* A    = (const float*)d_in[1];   // [KM, NN, NN]
    const int*   ei   = (const int*)  d_in[2];   // [2, NE]
    const float* wlog = (const float*)d_in[3];   // [KM]
    const float* Wm   = (const float*)d_in[4];   // [DD, DD]
    const float* b    = (const float*)d_in[5];   // [DD]
    float* out = (float*)d_out;                  // [NN, DD]

    float* ws   = (float*)d_ws;
    float* ew   = ws;                         // NE
    float* deg  = ws + NE;                    // NN
    float* dinv = ws + NE + NN;               // NN
    float* xw   = ws + NE + 2 * NN;           // NN*DD (16B aligned)

    // zero the degree accumulator (ws is poisoned 0xAA before every launch)
    hipMemsetAsync(deg, 0, NN * sizeof(float), stream);

    edge_w_kernel<<<NE / 256, 256, 0, stream>>>(A, ei, wlog, ew, deg);
    xw_gemm_kernel<<<NN / GEMM_ROWS, 256, 0, stream>>>(x, Wm, xw);
    node_init_kernel<<<(NN * 32) / 256, 256, 0, stream>>>(deg, xw, b, dinv, out);
    aggregate_kernel<<<(NE * 32) / 256, 256, 0, stream>>>(ei, ew, dinv, xw, out);
}